// Round 2
// 474.819 us; speedup vs baseline: 1.1041x; 1.1041x over previous
//
#include <hip/hip_runtime.h>
#include <hip/hip_bf16.h>
#include <cstdint>

typedef unsigned short u16;
typedef __bf16 bf16x8 __attribute__((ext_vector_type(8)));
typedef float  f32x4  __attribute__((ext_vector_type(4)));

typedef const __attribute__((address_space(1))) void* gptr_t;
typedef __attribute__((address_space(3))) void*       sptr_t;

#define IN_DIM  1024
#define OUT_DIM 2048
#define NROWS   8192            // 4*2048 samples
#define NB      8               // GRID + K   (basis functions per d)
#define KTOT    (IN_DIM * 9)    // 9216: k<8192 -> spline d*8+g ; k>=8192 -> silu d
#define KSPL    (IN_DIM * 8)    // 8192

#define WT_O 16                 // wt transpose tile: 16 o x 64 d
#define WT_D 64
#define TR_BLOCKS ((NROWS / 64) * (IN_DIM / 64))        // 2048 x-transpose blocks (tier-2)
#define WT_BLOCKS ((OUT_DIM / WT_O) * (IN_DIM / WT_D))  // 2048 wt blocks
#define ACT_BLOCKS ((NROWS / 64) * (IN_DIM / 64))       // 2048 act-build blocks (tier-1)

// Tier-1 GEMM geometry: 256x256 tile, BK=32, 4-deep K-tile pipeline.
#define BK 32
#define TILE_U16 (256 * BK)     // 8192 u16 = 16 KB per K-tile buffer (per matrix)
#define NKT (KTOT / BK)         // 288

__device__ __forceinline__ float rcp_fast(float v) { return __builtin_amdgcn_rcpf(v); }

// fp32 -> bf16 round-to-nearest-even bit pattern (finite inputs only)
__device__ __forceinline__ u16 f2b(float v) {
  uint32_t u = __float_as_uint(v);
  uint32_t r = (u + 0x7FFFu + ((u >> 16) & 1u)) >> 16;
  return (u16)r;
}

// pack two fp32 -> packed bf16x2 (a in low half), RNE
__device__ __forceinline__ uint32_t pkbf(float a, float b) {
  return (uint32_t)f2b(a) | ((uint32_t)f2b(b) << 16);
}

// Uniform-knot cardinal cubic: 8 spline channels for one x, packed as 4x u32
// (bf16 pairs, channel g ascending). j=floor((x+1)*2.5) in [0,4], u=frac;
// nonzero channels j..j+3 = {(1-u)^3, 3u^3-6u^2+4, -3u^3+3u^2+3u+1, u^3}/6.
__device__ __forceinline__ uint4 basis_pack(float xval) {
  float tt = (xval + 1.0f) * 2.5f;
  float jf = floorf(tt);
  jf = fminf(fmaxf(jf, 0.0f), 4.0f);
  const float u = tt - jf;
  const int j = (int)jf;
  const float um = 1.0f - u;
  const float u2 = u * u, u3 = u2 * u;
  const float b0 = um * um * um * (1.0f / 6.0f);
  const float b1 = (3.0f * u3 - 6.0f * u2 + 4.0f) * (1.0f / 6.0f);
  const float b2 = (-3.0f * u3 + 3.0f * u2 + 3.0f * u + 1.0f) * (1.0f / 6.0f);
  const float b3 = u3 * (1.0f / 6.0f);
  const uint32_t e01 = pkbf(b0, b1), e23 = pkbf(b2, b3);
  const uint32_t o0 = e01 << 16;                      // (0, h0)
  const uint32_t o12 = (e01 >> 16) | (e23 << 16);     // (h1, h2)
  const uint32_t o3 = e23 >> 16;                      // (h3, 0)
  const int odd = j & 1, m = j >> 1;
  const uint32_t a0 = odd ? o0 : e01;
  const uint32_t a1 = odd ? o12 : e23;
  const uint32_t a2 = odd ? o3 : 0u;
  uint4 wv;
  wv.x = (m == 0) ? a0 : 0u;
  wv.y = (m == 1) ? a0 : ((m == 0) ? a1 : 0u);
  wv.z = (m == 2) ? a0 : ((m == 1) ? a1 : ((m == 0) ? a2 : 0u));
  wv.w = (m == 2) ? a1 : ((m == 1) ? a2 : 0u);
  return wv;
}

// ---------------------------------------------------------------------------
// TIER-1 prep: blocks [0,ACT_BLOCKS) materialize act[n][k] bf16
// (k<8192: spline basis d*8+g ; k>=8192: silu(x[n][d])). Blocks
// [ACT_BLOCKS,+WT_BLOCKS) build Wt[o][k] (coef*scale_sp / scale_base) bf16.
// Basis is computed exactly ONCE per (n,d) here instead of 16x in the GEMM.
// ---------------------------------------------------------------------------
__global__ __launch_bounds__(256) void kan_prep2(const float* __restrict__ x,
                                                 const float* __restrict__ coef,
                                                 const float* __restrict__ scale_base,
                                                 const float* __restrict__ scale_sp,
                                                 u16* __restrict__ act,
                                                 u16* __restrict__ wt) {
  const int t = threadIdx.x;

  if (blockIdx.x < ACT_BLOCKS) {
    // ---- act tile: 64 n x 64 d ----
    __shared__ __align__(16) u16 st[64][72];   // silu staging (pad 72 breaks banks)
    const int bi = blockIdx.x;
    const int n0 = (bi & 127) * 64;
    const int d0 = (bi >> 7) * 64;
    const int dl = t & 63, r0 = t >> 6;        // r0 in 0..3
#pragma unroll
    for (int i = 0; i < 16; ++i) {
      const int r = r0 + i * 4;
      const float v = x[(size_t)(n0 + r) * IN_DIM + d0 + dl];
      *(uint4*)&act[(size_t)(n0 + r) * KTOT + (size_t)(d0 + dl) * 8] = basis_pack(v);
      st[r][dl] = f2b(v * rcp_fast(1.0f + __expf(-v)));
    }
    __syncthreads();
#pragma unroll
    for (int j = 0; j < 2; ++j) {
      const int idx = t + j * 256;
      const int r = idx >> 3, c8 = idx & 7;
      *(uint4*)&act[(size_t)(n0 + r) * KTOT + KSPL + d0 + c8 * 8] =
          *(const uint4*)&st[r][c8 * 8];
    }
  } else {
    // ---- Wt path: 16o x 64d transpose tile ----
    __shared__ __align__(16) u16 tsp[WT_O][WT_D * 8 + 8];
    __shared__ __align__(16) u16 tsi[WT_O][WT_D + 8];
    const int bi = blockIdx.x - ACT_BLOCKS;
    const int o0 = (bi % (OUT_DIM / WT_O)) * WT_O;
    const int d0 = (bi / (OUT_DIM / WT_O)) * WT_D;
    const int ol = t & (WT_O - 1), dl0 = t >> 4;  // dl0 in 0..15
#pragma unroll
    for (int rep = 0; rep < WT_D / 16; ++rep) {
      const int dl = rep * 16 + dl0;
      const int d = d0 + dl, o = o0 + ol;
      const size_t doff = (size_t)d * OUT_DIM + o;
      const float ssp = scale_sp[doff];
      const float sbv = scale_base[doff];
      const float4* cp = (const float4*)(coef + doff * 8);
      float4 c0 = cp[0], c1 = cp[1];
      uint4 val;
      val.x = pkbf(c0.x * ssp, c0.y * ssp);
      val.y = pkbf(c0.z * ssp, c0.w * ssp);
      val.z = pkbf(c1.x * ssp, c1.y * ssp);
      val.w = pkbf(c1.z * ssp, c1.w * ssp);
      *(uint4*)&tsp[ol][dl * 8] = val;
      tsi[ol][dl] = f2b(sbv);
    }
    __syncthreads();
    for (int i = t; i < WT_O * 64; i += 256) {
      const int row = i >> 6, col = i & 63;
      *(uint4*)(wt + (size_t)(o0 + row) * KTOT + (size_t)(d0 + col) * 8) =
          *(const uint4*)&tsp[row][col * 8];
    }
    if (t < WT_O * 8) {
      const int row = t >> 3, col = t & 7;
      *(uint4*)(wt + (size_t)(o0 + row) * KTOT + KSPL + d0 + col * 8) =
          *(const uint4*)&tsi[row][col * 8];
    }
  }
}

// ---------------------------------------------------------------------------
// TIER-1 GEMM: C[8192x2048] = act * Wt^T, pure bf16 MFMA GEMM.
// 256x256 tile, BK=32, 512 thr (8 waves = 2M x 4N), 4-deep K-tile pipeline:
//   stage tile t+3 -> counted s_waitcnt vmcnt(12) -> barrier -> ds_read frags
//   -> setprio(1) 32x MFMA setprio(0) -> barrier.
// LDS: 4 bufs x (A 16KB + B 16KB) = 128 KiB, 1 block/CU.
// Chunk swizzle phys = log ^ ((row>>1)&3) applied on the pre-swizzled GLOBAL
// source (global_load_lds dest stays linear, m173) and on ds_read addresses:
// read pattern lands exactly 2 lanes/bank (free).
// ---------------------------------------------------------------------------
__global__ __launch_bounds__(512, 2) void kan_gemm2(const u16* __restrict__ act,
                                                    const u16* __restrict__ Bt,
                                                    float* __restrict__ C) {
  __shared__ __align__(16) u16 As[4 * TILE_U16];  // 64 KB
  __shared__ __align__(16) u16 Bs[4 * TILE_U16];  // 64 KB
  const int tid  = threadIdx.x;
  const int lane = tid & 63;
  const int w    = tid >> 6;            // 0..7
  const int wm   = w >> 2, wn = w & 3;  // 2 x 4 wave grid
  const int q    = lane >> 4, m16 = lane & 15;

  // Bijective XCD swizzle: 256 wgs = 8 XCDs x 32; gx fastest so the 8 blocks
  // sharing an A row-panel land on one XCD's L2.
  const int bid = (blockIdx.x & 7) * 32 + (blockIdx.x >> 3);
  const int gx = bid & 7;    // o-tile   (N/256 = 8)
  const int gy = bid >> 3;   // row-tile (M/256 = 32)

  f32x4 acc[8][4];
#pragma unroll
  for (int i = 0; i < 8; ++i)
#pragma unroll
    for (int j = 0; j < 4; ++j) acc[i][j] = (f32x4){0.f, 0.f, 0.f, 0.f};

  // Staging: per K-tile each matrix is 256x32 bf16 = 16 KB = 16 wave-issues;
  // wave w covers rows [w*32, w*32+32) via 2 issues of 16 rows (1 KB each).
  // Lane l -> row w*32 + i*16 + (l>>2), phys chunk l&3; source logical chunk
  // = (l&3) ^ ((row>>1)&3) = (l&3) ^ ((l>>3)&3)  (w,i terms vanish mod 4).
  const int rA  = lane >> 2;
  const int csw = ((lane & 3) ^ ((lane >> 3) & 3)) * 8;  // u16 offset
  const u16* gA = act + (size_t)(gy * 256 + w * 32 + rA) * KTOT + csw;
  const u16* gB = Bt  + (size_t)(gx * 256 + w * 32 + rA) * KTOT + csw;
  const int ldsw = w * 1024;  // u16 offset of this wave's 32-row segment

#define STAGE(T)                                                               \
  do {                                                                         \
    const int _buf = (T) & 3;                                                  \
    const size_t _k0 = (size_t)(T) * BK;                                       \
    const u16* _ga = gA + _k0;                                                 \
    const u16* _gb = gB + _k0;                                                 \
    u16* _la = &As[_buf * TILE_U16 + ldsw];                                    \
    u16* _lb = &Bs[_buf * TILE_U16 + ldsw];                                    \
    __builtin_amdgcn_global_load_lds((gptr_t)_ga, (sptr_t)_la, 16, 0, 0);      \
    __builtin_amdgcn_global_load_lds((gptr_t)(_ga + (size_t)16 * KTOT),        \
                                     (sptr_t)(_la + 512), 16, 0, 0);           \
    __builtin_amdgcn_global_load_lds((gptr_t)_gb, (sptr_t)_lb, 16, 0, 0);      \
    __builtin_amdgcn_global_load_lds((gptr_t)(_gb + (size_t)16 * KTOT),        \
                                     (sptr_t)(_lb + 512), 16, 0, 0);           \
  } while (0)

  // Fragment reads: row base (wm*128 | wn*64) + frag*16 + m16, phys chunk
  // q ^ ((m16>>1)&3) (frag-independent since frag*16 is 0 mod 4 after >>1).
  const int px8 = (q ^ ((m16 >> 1) & 3)) * 8;
  const int aoff = (wm * 128 + m16) * 32 + px8;
  const int boff = (wn * 64 + m16) * 32 + px8;

#define COMPUTE(T)                                                             \
  do {                                                                         \
    const int _buf = (T) & 3;                                                  \
    const u16* _A = &As[_buf * TILE_U16 + aoff];                               \
    const u16* _B = &Bs[_buf * TILE_U16 + boff];                               \
    bf16x8 _bf[4];                                                             \
    _Pragma("unroll") for (int nt = 0; nt < 4; ++nt)                           \
        _bf[nt] = *(const bf16x8*)&_B[nt * 512];                               \
    bf16x8 _af[8];                                                             \
    _Pragma("unroll") for (int mt = 0; mt < 8; ++mt)                           \
        _af[mt] = *(const bf16x8*)&_A[mt * 512];                               \
    __builtin_amdgcn_s_setprio(1);                                             \
    _Pragma("unroll") for (int mt = 0; mt < 8; ++mt)                           \
      _Pragma("unroll") for (int nt = 0; nt < 4; ++nt)                         \
          acc[mt][nt] = __builtin_amdgcn_mfma_f32_16x16x32_bf16(               \
              _af[mt], _bf[nt], acc[mt][nt], 0, 0, 0);                         \
    __builtin_amdgcn_s_setprio(0);                                             \
  } while (0)

#define KSTEP(T, VM, DOSTAGE)                                                  \
  do {                                                                         \
    if (DOSTAGE) STAGE((T) + 3);                                               \
    asm volatile("s_waitcnt vmcnt(" #VM ")" ::: "memory");                     \
    __builtin_amdgcn_s_barrier();                                              \
    COMPUTE(T);                                                                \
    asm volatile("" ::: "memory");                                             \
    __builtin_amdgcn_s_barrier();                                              \
  } while (0)

  // Prologue: fill 3 K-tiles (12 issues/thread in flight).
  STAGE(0);
  STAGE(1);
  STAGE(2);

  // Main loop: 284 = 71*4 steps, buffer index compile-time per unrolled j.
  for (int tb = 0; tb < 71; ++tb) {
#pragma unroll
    for (int j = 0; j < 4; ++j) {
      const int t = tb * 4 + j;
      KSTEP(t, 12, true);
    }
  }
  KSTEP(284, 12, true);   // stages tile 287 (last)
  KSTEP(285, 8, false);
  KSTEP(286, 4, false);
  KSTEP(287, 0, false);

#undef KSTEP
#undef COMPUTE
#undef STAGE

  // Epilogue: C/D layout col = lane&15, row = (lane>>4)*4 + reg (m89-verified)
  const int row_base = gy * 256 + wm * 128 + q * 4;
  const int col_base = gx * 256 + wn * 64 + m16;
#pragma unroll
  for (int mt = 0; mt < 8; ++mt) {
#pragma unroll
    for (int nt = 0; nt < 4; ++nt) {
      const int r0 = row_base + mt * 16;
      const int c  = col_base + nt * 16;
#pragma unroll
      for (int r = 0; r < 4; ++r)
        C[(size_t)(r0 + r) * OUT_DIM + c] = acc[mt][nt][r];
    }
  }
}

// ---------------------------------------------------------------------------
// TIER-2 (previous best, ws >= 88MB): on-the-fly A, 128^2 tile. Kept intact.
// ---------------------------------------------------------------------------
__global__ __launch_bounds__(256) void kan_prep(const float* __restrict__ x,
                                                const float* __restrict__ coef,
                                                const float* __restrict__ scale_base,
                                                const float* __restrict__ scale_sp,
                                                float* __restrict__ xT,
                                                u16* __restrict__ sil,
                                                u16* __restrict__ wt) {
  const int t = threadIdx.x;

  if (blockIdx.x < TR_BLOCKS) {
    __shared__ float tile[64][65];
    const int bi = blockIdx.x;
    const int n0 = (bi & 127) * 64;
    const int d0 = (bi >> 7) * 64;
    const int col = t & 63, rbase = t >> 6;
#pragma unroll
    for (int i = 0; i < 16; ++i) {
      const int r = rbase + i * 4;
      const float v = x[(size_t)(n0 + r) * IN_DIM + d0 + col];
      tile[r][col] = v;
      sil[(size_t)(n0 + r) * IN_DIM + d0 + col] =
          f2b(v * rcp_fast(1.0f + __expf(-v)));
    }
    __syncthreads();
#pragma unroll
    for (int i = 0; i < 16; ++i) {
      const int dd = rbase + i * 4;
      xT[(size_t)(d0 + dd) * NROWS + n0 + col] = tile[col][dd];
    }
  } else {
    __shared__ __align__(16) u16 tsp[WT_O][WT_D * 8 + 8];
    __shared__ __align__(16) u16 tsi[WT_O][WT_D + 8];
    const int bi = blockIdx.x - TR_BLOCKS;
    const int o0 = (bi % (OUT_DIM / WT_O)) * WT_O;
    const int d0 = (bi / (OUT_DIM / WT_O)) * WT_D;
    const int ol = t & (WT_O - 1), dl0 = t >> 4;
#pragma unroll
    for (int rep = 0; rep < WT_D / 16; ++rep) {
      const int dl = rep * 16 + dl0;
      const int d = d0 + dl, o = o0 + ol;
      const size_t doff = (size_t)d * OUT_DIM + o;
      const float ssp = scale_sp[doff];
      const float sbv = scale_base[doff];
      const float4* cp = (const float4*)(coef + doff * 8);
      float4 c0 = cp[0], c1 = cp[1];
      uint4 val;
      val.x = pkbf(c0.x * ssp, c0.y * ssp);
      val.y = pkbf(c0.z * ssp, c0.w * ssp);
      val.z = pkbf(c1.x * ssp, c1.y * ssp);
      val.w = pkbf(c1.z * ssp, c1.w * ssp);
      *(uint4*)&tsp[ol][dl * 8] = val;
      tsi[ol][dl] = f2b(sbv);
    }
    __syncthreads();
    for (int i = t; i < WT_O * 64; i += 256) {
      const int row = i >> 6, col = i & 63;
      *(uint4*)(wt + (size_t)(o0 + row) * KTOT + (size_t)(d0 + col) * 8) =
          *(const uint4*)&tsp[row][col * 8];
    }
    if (t < WT_O * 8) {
      const int row = t >> 3, col = t & 7;
      *(uint4*)(wt + (size_t)(o0 + row) * KTOT + KSPL + d0 + col * 8) =
          *(const uint4*)&tsi[row][col * 8];
    }
  }
}

__global__ __launch_bounds__(256) void kan_gemm(const float* __restrict__ xT,
                                                const u16* __restrict__ sil,
                                                const u16* __restrict__ Bt,
                                                float* __restrict__ C) {
  __shared__ __align__(16) u16 As[128 * 64];
  __shared__ __align__(16) u16 Bs[128 * 64];
  const int tid  = threadIdx.x;
  const int lane = tid & 63;
  const int w    = tid >> 6;
  const int wm   = w >> 1, wn = w & 1;
  const int q    = lane >> 4, m16 = lane & 15;
  const int gx = blockIdx.x, gy = blockIdx.y;

  f32x4 acc[4][4];
#pragma unroll
  for (int i = 0; i < 4; ++i)
#pragma unroll
    for (int j = 0; j < 4; ++j) acc[i][j] = (f32x4){0.f, 0.f, 0.f, 0.f};

  const int srow = lane >> 3;
  const int swzc = (lane & 7) ^ srow;
  const u16* gb0 = Bt + (size_t)(gx * 128) * KTOT + swzc * 8;
  const int r7 = m16 & 15 & 7;
  const int dgrp = tid >> 5;
  const int nh   = tid & 31;

  for (int kk = 0; kk < KTOT; kk += 64) {
#pragma unroll
    for (int i = 0; i < 4; ++i) {
      const int rg = w * 32 + i * 8;
      __builtin_amdgcn_global_load_lds((gptr_t)(gb0 + (size_t)(rg + srow) * KTOT + kk),
                                       (sptr_t)&Bs[rg * 64], 16, 0, 0);
    }
    if (kk < KSPL) {
      const int d = (kk >> 3) + dgrp;
      const float4 xv = *(const float4*)(xT + (size_t)d * NROWS + gy * 128 + nh * 4);
      const float xa[4] = {xv.x, xv.y, xv.z, xv.w};
#pragma unroll
      for (int r = 0; r < 4; ++r) {
        const int row = nh * 4 + r;
        const uint4 wv = basis_pack(xa[r]);
        *(uint4*)&As[row * 64 + ((dgrp ^ (row & 7)) * 8)] = wv;
      }
    } else {
      const int kb = kk - KSPL;
#pragma unroll
      for (int i = 0; i < 4; ++i) {
        const int rg = w * 32 + i * 8;
        __builtin_amdgcn_global_load_lds(
            (gptr_t)(sil + (size_t)(gy * 128 + rg + srow) * IN_DIM + kb + swzc * 8),
            (sptr_t)&As[rg * 64], 16, 0, 0);
      }
    }
    __syncthreads();
#pragma unroll
    for (int ks = 0; ks < 64; ks += 32) {
      const int pc = ((ks >> 3) + q) ^ r7;
      bf16x8 af[4], bf[4];
#pragma unroll
      for (int mt = 0; mt < 4; ++mt)
        af[mt] = *(const bf16x8*)&As[(wm * 64 + mt * 16 + m16) * 64 + pc * 8];
#pragma unroll
      for (int nt = 0; nt < 4; ++nt)
        bf[nt] = *(const bf16x8*)&Bs[(wn * 64 + nt * 16 + m16) * 64 + pc * 8];
#pragma unroll
      for (int mt = 0; mt < 4; ++mt)
#pragma unroll
        for (int nt = 0; nt < 4; ++nt)
          acc[mt][nt] = __builtin_amdgcn_mfma_f32_16x16x32_bf16(af[mt], bf[nt],
                                                                acc[mt][nt], 0, 0, 0);
    }
    __syncthreads();
  }

#pragma unroll
  for (int mt = 0; mt < 4; ++mt) {
    const int row0 = gy * 128 + wm * 64 + mt * 16 + q * 4;
#pragma unroll
    for (int nt = 0; nt < 4; ++nt) {
      const int col = gx * 128 + wn * 64 + nt * 16 + m16;
#pragma unroll
      for (int r = 0; r < 4; ++r)
        C[(size_t)(row0 + r) * OUT_DIM + col] = acc[mt][nt][r];
    }
  }
}

// ---------------------------------------------------------------------------
// Fallback (workspace too small): fused direct fp32 computation.
// ---------------------------------------------------------------------------
__global__ __launch_bounds__(256) void kan_fallback(const float* __restrict__ x,
                                                    const float* __restrict__ grid,
                                                    const float* __restrict__ coef,
                                                    const float* __restrict__ scale_base,
                                                    const float* __restrict__ scale_sp,
                                                    float* __restrict__ out) {
  __shared__ float bs[IN_DIM * 9];  // 36 KB
  const int n = blockIdx.x;
  const int t = threadIdx.x;
#pragma unroll
  for (int dd = 0; dd < IN_DIM / 256; ++dd) {
    const int d = t + dd * 256;
    const float xv = x[(size_t)n * IN_DIM + d];
    float tt = (xv + 1.0f) * 2.5f;
    float jf = floorf(tt);
    jf = fminf(fmaxf(jf, 0.0f), 4.0f);
    const float u = tt - jf;
    const int j = (int)jf;
    const float um = 1.0f - u;
    const float u2 = u * u, u3 = u2 * u;
    float* r = &bs[d * 9];
#pragma unroll
    for (int g = 0; g < NB; ++g) r[g] = 0.0f;
    r[j]     = um * um * um * (1.0f / 6.0f);
    r[j + 1] = (3.0f * u3 - 6.0f * u2 + 4.0f) * (1.0f / 6.0f);
    r[j + 2] = (-3.0f * u3 + 3.0f * u2 + 3.0f * u + 1.0f) * (1.0f / 6.0f);
    r[j + 3] = u3 * (1.0f / 6.0f);
    r[8]     = xv * rcp_fast(1.0f + __expf(-xv));
  }
  __syncthreads();
  const int o = blockIdx.y * 256 + t;
  float acc = 0.0f;
  for (int d = 0; d < IN_DIM; ++d) {
    const size_t doff = (size_t)d * OUT_DIM + o;
    const float4* cp = (const float4*)(coef + doff * 8);
    float4 c0 = cp[0], c1 = cp[1];
    const float* b = &bs[d * 9];
    float s = b[0] * c0.x + b[1] * c0.y + b[2] * c0.z + b[3] * c0.w +
              b[4] * c1.x + b[5] * c1.y + b[6] * c1.z + b[7] * c1.w;
    acc += s * scale_sp[doff] + b[8] * scale_base[doff];
  }
  out[(size_t)n * OUT_DIM + o] = acc;
}

extern "C" void kernel_launch(void* const* d_in, const int* in_sizes, int n_in,
                              void* d_out, int out_size, void* d_ws, size_t ws_size,
                              hipStream_t stream) {
  const float* x  = (const float*)d_in[0];  // (4,2048,1024)
  const float* gr = (const float*)d_in[1];  // (1024,12)  (uniform; unused in fast path)
  const float* cf = (const float*)d_in[2];  // (1024,2048,8)
  const float* sb = (const float*)d_in[3];  // (1024,2048)
  const float* sp = (const float*)d_in[4];  // (1024,2048)
  float* out = (float*)d_out;               // (4,2048,2048)

  const size_t act_bytes = (size_t)NROWS * KTOT * sizeof(u16);    // 151 MB
  const size_t wt_bytes  = (size_t)OUT_DIM * KTOT * sizeof(u16);  // 37.7 MB
  const size_t need1 = act_bytes + wt_bytes;                      // ~189 MB

  const size_t xT_bytes  = (size_t)IN_DIM * NROWS * sizeof(float);  // 33.5 MB
  const size_t sil_bytes = (size_t)NROWS * IN_DIM * sizeof(u16);    // 16.8 MB
  const size_t need2 = xT_bytes + sil_bytes + wt_bytes;             // ~88 MB

  if (ws_size >= need1) {
    u16* act = (u16*)d_ws;
    u16* wt  = (u16*)((char*)d_ws + act_bytes);
    kan_prep2<<<dim3(ACT_BLOCKS + WT_BLOCKS), dim3(256), 0, stream>>>(
        x, cf, sb, sp, act, wt);
    kan_gemm2<<<dim3(256), dim3(512), 0, stream>>>(act, wt, out);
  } else if (ws_size >= need2) {
    float* xT = (float*)d_ws;
    u16* sil  = (u16*)((char*)d_ws + xT_bytes);
    u16* wt   = (u16*)((char*)d_ws + xT_bytes + sil_bytes);
    kan_prep<<<dim3(TR_BLOCKS + WT_BLOCKS), dim3(256), 0, stream>>>(
        x, cf, sb, sp, xT, sil, wt);
    kan_gemm<<<dim3(OUT_DIM / 128, NROWS / 128), dim3(256), 0, stream>>>(
        xT, sil, wt, out);
  } else {
    kan_fallback<<<dim3(NROWS, OUT_DIM / 256), dim3(256), 0, stream>>>(x, gr, cf, sb, sp, out);
  }
}

// Round 3
// 443.901 us; speedup vs baseline: 1.1810x; 1.0697x over previous
//
#include <hip/hip_runtime.h>
#include <hip/hip_bf16.h>
#include <cstdint>

typedef unsigned short u16;
typedef __bf16 bf16x8 __attribute__((ext_vector_type(8)));
typedef float  f32x4  __attribute__((ext_vector_type(4)));

typedef const __attribute__((address_space(1))) void* gptr_t;
typedef __attribute__((address_space(3))) void*       sptr_t;

#define IN_DIM  1024
#define OUT_DIM 2048
#define NROWS   8192            // 4*2048 samples
#define NB      8               // GRID + K   (basis functions per d)
#define KTOT    (IN_DIM * 9)    // 9216: k<8192 -> spline d*8+g ; k>=8192 -> silu d
#define KSPL    (IN_DIM * 8)    // 8192

#define WT_O 16                 // wt transpose tile: 16 o x 64 d
#define WT_D 64
#define TR_BLOCKS ((NROWS / 64) * (IN_DIM / 64))        // 2048 x-transpose blocks (tier-2)
#define WT_BLOCKS ((OUT_DIM / WT_O) * (IN_DIM / WT_D))  // 2048 wt blocks
#define ACT_BLOCKS ((NROWS / 64) * (IN_DIM / 64))       // 2048 act-build blocks (tier-1)

// Tier-1 GEMM geometry: 256x256 tile, BK=32, 4-deep K-tile pipeline.
#define BK 32
#define TILE_U16 (256 * BK)     // 8192 u16 = 16 KB per K-tile buffer (per matrix)
#define NKT (KTOT / BK)         // 288

__device__ __forceinline__ float rcp_fast(float v) { return __builtin_amdgcn_rcpf(v); }

// fp32 -> bf16 round-to-nearest-even bit pattern (finite inputs only)
__device__ __forceinline__ u16 f2b(float v) {
  uint32_t u = __float_as_uint(v);
  uint32_t r = (u + 0x7FFFu + ((u >> 16) & 1u)) >> 16;
  return (u16)r;
}

// pack two fp32 -> packed bf16x2 (a in low half), RNE
__device__ __forceinline__ uint32_t pkbf(float a, float b) {
  return (uint32_t)f2b(a) | ((uint32_t)f2b(b) << 16);
}

// Uniform-knot cardinal cubic: 8 spline channels for one x, packed as 4x u32
// (bf16 pairs, channel g ascending). j=floor((x+1)*2.5) in [0,4], u=frac;
// nonzero channels j..j+3 = {(1-u)^3, 3u^3-6u^2+4, -3u^3+3u^2+3u+1, u^3}/6.
__device__ __forceinline__ uint4 basis_pack(float xval) {
  float tt = (xval + 1.0f) * 2.5f;
  float jf = floorf(tt);
  jf = fminf(fmaxf(jf, 0.0f), 4.0f);
  const float u = tt - jf;
  const int j = (int)jf;
  const float um = 1.0f - u;
  const float u2 = u * u, u3 = u2 * u;
  const float b0 = um * um * um * (1.0f / 6.0f);
  const float b1 = (3.0f * u3 - 6.0f * u2 + 4.0f) * (1.0f / 6.0f);
  const float b2 = (-3.0f * u3 + 3.0f * u2 + 3.0f * u + 1.0f) * (1.0f / 6.0f);
  const float b3 = u3 * (1.0f / 6.0f);
  const uint32_t e01 = pkbf(b0, b1), e23 = pkbf(b2, b3);
  const uint32_t o0 = e01 << 16;                      // (0, h0)
  const uint32_t o12 = (e01 >> 16) | (e23 << 16);     // (h1, h2)
  const uint32_t o3 = e23 >> 16;                      // (h3, 0)
  const int odd = j & 1, m = j >> 1;
  const uint32_t a0 = odd ? o0 : e01;
  const uint32_t a1 = odd ? o12 : e23;
  const uint32_t a2 = odd ? o3 : 0u;
  uint4 wv;
  wv.x = (m == 0) ? a0 : 0u;
  wv.y = (m == 1) ? a0 : ((m == 0) ? a1 : 0u);
  wv.z = (m == 2) ? a0 : ((m == 1) ? a1 : ((m == 0) ? a2 : 0u));
  wv.w = (m == 2) ? a1 : ((m == 1) ? a2 : 0u);
  return wv;
}

// ---------------------------------------------------------------------------
// TIER-1 prep: blocks [0,ACT_BLOCKS) materialize act[n][k] bf16
// (k<8192: spline basis d*8+g ; k>=8192: silu(x[n][d])). Blocks
// [ACT_BLOCKS,+WT_BLOCKS) build Wt[o][k] (coef*scale_sp / scale_base) bf16.
// ---------------------------------------------------------------------------
__global__ __launch_bounds__(256) void kan_prep2(const float* __restrict__ x,
                                                 const float* __restrict__ coef,
                                                 const float* __restrict__ scale_base,
                                                 const float* __restrict__ scale_sp,
                                                 u16* __restrict__ act,
                                                 u16* __restrict__ wt) {
  const int t = threadIdx.x;

  if (blockIdx.x < ACT_BLOCKS) {
    // ---- act tile: 64 n x 64 d ----
    __shared__ __align__(16) u16 st[64][72];   // silu staging (pad 72 breaks banks)
    const int bi = blockIdx.x;
    const int n0 = (bi & 127) * 64;
    const int d0 = (bi >> 7) * 64;
    const int dl = t & 63, r0 = t >> 6;        // r0 in 0..3
#pragma unroll
    for (int i = 0; i < 16; ++i) {
      const int r = r0 + i * 4;
      const float v = x[(size_t)(n0 + r) * IN_DIM + d0 + dl];
      *(uint4*)&act[(size_t)(n0 + r) * KTOT + (size_t)(d0 + dl) * 8] = basis_pack(v);
      st[r][dl] = f2b(v * rcp_fast(1.0f + __expf(-v)));
    }
    __syncthreads();
#pragma unroll
    for (int j = 0; j < 2; ++j) {
      const int idx = t + j * 256;
      const int r = idx >> 3, c8 = idx & 7;
      *(uint4*)&act[(size_t)(n0 + r) * KTOT + KSPL + d0 + c8 * 8] =
          *(const uint4*)&st[r][c8 * 8];
    }
  } else {
    // ---- Wt path: 16o x 64d transpose tile ----
    __shared__ __align__(16) u16 tsp[WT_O][WT_D * 8 + 8];
    __shared__ __align__(16) u16 tsi[WT_O][WT_D + 8];
    const int bi = blockIdx.x - ACT_BLOCKS;
    const int o0 = (bi % (OUT_DIM / WT_O)) * WT_O;
    const int d0 = (bi / (OUT_DIM / WT_O)) * WT_D;
    const int ol = t & (WT_O - 1), dl0 = t >> 4;  // dl0 in 0..15
#pragma unroll
    for (int rep = 0; rep < WT_D / 16; ++rep) {
      const int dl = rep * 16 + dl0;
      const int d = d0 + dl, o = o0 + ol;
      const size_t doff = (size_t)d * OUT_DIM + o;
      const float ssp = scale_sp[doff];
      const float sbv = scale_base[doff];
      const float4* cp = (const float4*)(coef + doff * 8);
      float4 c0 = cp[0], c1 = cp[1];
      uint4 val;
      val.x = pkbf(c0.x * ssp, c0.y * ssp);
      val.y = pkbf(c0.z * ssp, c0.w * ssp);
      val.z = pkbf(c1.x * ssp, c1.y * ssp);
      val.w = pkbf(c1.z * ssp, c1.w * ssp);
      *(uint4*)&tsp[ol][dl * 8] = val;
      tsi[ol][dl] = f2b(sbv);
    }
    __syncthreads();
    for (int i = t; i < WT_O * 64; i += 256) {
      const int row = i >> 6, col = i & 63;
      *(uint4*)(wt + (size_t)(o0 + row) * KTOT + (size_t)(d0 + col) * 8) =
          *(const uint4*)&tsp[row][col * 8];
    }
    if (t < WT_O * 8) {
      const int row = t >> 3, col = t & 7;
      *(uint4*)(wt + (size_t)(o0 + row) * KTOT + KSPL + d0 + col * 8) =
          *(const uint4*)&tsi[row][col * 8];
    }
  }
}

// ---------------------------------------------------------------------------
// TIER-1 GEMM: C[8192x2048] = act * Wt^T, pure bf16 MFMA GEMM.
// 256x256 tile, BK=32, 512 thr (8 waves = 2M x 4N), 4-deep K-tile LDS pipe
// PLUS register fragment prefetch: region t's 32 MFMAs consume fragments
// loaded in region t-1 (no lgkm dependency), while the 12 ds_read_b128 for
// tile t+1 interleave into the MFMA stream (fa[mt] reloaded right after its
// last use -> zero extra register sets; acc already holds 128 AGPRs).
// vmcnt(8) each region guarantees tile t+2 resident before region t+1 reads
// it; lgkmcnt(0) before the single trailing barrier closes the cross-wave
// WAR window (reads of buf b retired before any wave's STAGE rewrites b).
// ---------------------------------------------------------------------------
__global__ __launch_bounds__(512, 2) void kan_gemm2(const u16* __restrict__ act,
                                                    const u16* __restrict__ Bt,
                                                    float* __restrict__ C) {
  __shared__ __align__(16) u16 As[4 * TILE_U16];  // 64 KB
  __shared__ __align__(16) u16 Bs[4 * TILE_U16];  // 64 KB
  const int tid  = threadIdx.x;
  const int lane = tid & 63;
  const int w    = tid >> 6;            // 0..7
  const int wm   = w >> 2, wn = w & 3;  // 2 x 4 wave grid
  const int q    = lane >> 4, m16 = lane & 15;

  // Bijective XCD swizzle: 256 wgs = 8 XCDs x 32; gx fastest so the 8 blocks
  // sharing an A row-panel land on one XCD's L2.
  const int bid = (blockIdx.x & 7) * 32 + (blockIdx.x >> 3);
  const int gx = bid & 7;    // o-tile   (N/256 = 8)
  const int gy = bid >> 3;   // row-tile (M/256 = 32)

  f32x4 acc[8][4];
#pragma unroll
  for (int i = 0; i < 8; ++i)
#pragma unroll
    for (int j = 0; j < 4; ++j) acc[i][j] = (f32x4){0.f, 0.f, 0.f, 0.f};

  // Staging: per K-tile each matrix is 256x32 bf16 = 16 KB = 16 wave-issues;
  // wave w covers rows [w*32, w*32+32) via 2 issues of 16 rows (1 KB each).
  // Lane l -> row w*32 + i*16 + (l>>2), phys chunk l&3; source logical chunk
  // = (l&3) ^ ((row>>1)&3) = (l&3) ^ ((l>>3)&3)  (w,i terms vanish mod 4).
  const int rA  = lane >> 2;
  const int csw = ((lane & 3) ^ ((lane >> 3) & 3)) * 8;  // u16 offset
  const u16* gA = act + (size_t)(gy * 256 + w * 32 + rA) * KTOT + csw;
  const u16* gB = Bt  + (size_t)(gx * 256 + w * 32 + rA) * KTOT + csw;
  const int ldsw = w * 1024;  // u16 offset of this wave's 32-row segment

#define STAGE(T)                                                               \
  do {                                                                         \
    const int _buf = (T) & 3;                                                  \
    const size_t _k0 = (size_t)(T) * BK;                                       \
    const u16* _ga = gA + _k0;                                                 \
    const u16* _gb = gB + _k0;                                                 \
    u16* _la = &As[_buf * TILE_U16 + ldsw];                                    \
    u16* _lb = &Bs[_buf * TILE_U16 + ldsw];                                    \
    __builtin_amdgcn_global_load_lds((gptr_t)_ga, (sptr_t)_la, 16, 0, 0);      \
    __builtin_amdgcn_global_load_lds((gptr_t)(_ga + (size_t)16 * KTOT),        \
                                     (sptr_t)(_la + 512), 16, 0, 0);           \
    __builtin_amdgcn_global_load_lds((gptr_t)_gb, (sptr_t)_lb, 16, 0, 0);      \
    __builtin_amdgcn_global_load_lds((gptr_t)(_gb + (size_t)16 * KTOT),        \
                                     (sptr_t)(_lb + 512), 16, 0, 0);           \
  } while (0)

  // Fragment reads: row base (wm*128 | wn*64) + frag*16 + m16, phys chunk
  // q ^ ((m16>>1)&3) (frag-independent since frag*16 is 0 mod 4 after >>1).
  const int px8 = (q ^ ((m16 >> 1) & 3)) * 8;
  const int aoff = (wm * 128 + m16) * 32 + px8;
  const int boff = (wn * 64 + m16) * 32 + px8;

  bf16x8 fa[8], fb[4];  // current-tile fragments (all indexing fully unrolled)

  // Region T: MFMA with fragments of tile T (in regs) while reloading
  // fragments of tile T+1 from LDS buf (T+1)&3 and staging tile T+4.
#define REGION(T, DOREAD, DOSTAGE, VM)                                         \
  do {                                                                         \
    const u16* _An = &As[(((T) + 1) & 3) * TILE_U16 + aoff];                   \
    const u16* _Bn = &Bs[(((T) + 1) & 3) * TILE_U16 + boff];                   \
    if (DOSTAGE) STAGE((T) + 4);                                               \
    __builtin_amdgcn_s_setprio(1);                                             \
    _Pragma("unroll") for (int mt = 0; mt < 8; ++mt) {                         \
      _Pragma("unroll") for (int nt = 0; nt < 4; ++nt)                         \
        acc[mt][nt] = __builtin_amdgcn_mfma_f32_16x16x32_bf16(                 \
            fa[mt], fb[nt], acc[mt][nt], 0, 0, 0);                             \
      if (DOREAD) fa[mt] = *(const bf16x8*)&_An[mt * 512];                     \
    }                                                                          \
    __builtin_amdgcn_s_setprio(0);                                             \
    if (DOREAD) {                                                              \
      _Pragma("unroll") for (int nt = 0; nt < 4; ++nt)                         \
        fb[nt] = *(const bf16x8*)&_Bn[nt * 512];                               \
    }                                                                          \
    asm volatile("s_waitcnt vmcnt(" #VM ")" ::: "memory");                     \
    asm volatile("s_waitcnt lgkmcnt(0)" ::: "memory");                         \
    __builtin_amdgcn_s_barrier();                                              \
  } while (0)

  // Prologue: fill 4 K-tiles (16 loads/thread); wait until tiles 0,1 landed
  // (vmcnt(8): newest 8 = tiles 2,3); then preload tile-0 fragments.
  STAGE(0);
  STAGE(1);
  STAGE(2);
  STAGE(3);
  asm volatile("s_waitcnt vmcnt(8)" ::: "memory");
  __builtin_amdgcn_s_barrier();
  {
    const u16* _A0 = &As[aoff];
    const u16* _B0 = &Bs[boff];
#pragma unroll
    for (int nt = 0; nt < 4; ++nt) fb[nt] = *(const bf16x8*)&_B0[nt * 512];
#pragma unroll
    for (int mt = 0; mt < 8; ++mt) fa[mt] = *(const bf16x8*)&_A0[mt * 512];
  }

  // Main: regions 0..283 stage tiles 4..287; vmcnt(8) -> tile t+2 landed.
  for (int tb = 0; tb < 71; ++tb) {
#pragma unroll
    for (int j = 0; j < 4; ++j) {
      REGION(tb * 4 + j, true, true, 8);
    }
  }
  // Tail: no more staging; drain 4 -> 0.
  REGION(284, true, false, 4);
  REGION(285, true, false, 0);
  REGION(286, true, false, 0);
  // Region 287: consume-only (fragments of tile 287 already in regs).
  __builtin_amdgcn_s_setprio(1);
#pragma unroll
  for (int mt = 0; mt < 8; ++mt)
#pragma unroll
    for (int nt = 0; nt < 4; ++nt)
      acc[mt][nt] = __builtin_amdgcn_mfma_f32_16x16x32_bf16(fa[mt], fb[nt],
                                                            acc[mt][nt], 0, 0, 0);
  __builtin_amdgcn_s_setprio(0);

#undef REGION
#undef STAGE

  // Epilogue: C/D layout col = lane&15, row = (lane>>4)*4 + reg (m89-verified)
  const int row_base = gy * 256 + wm * 128 + q * 4;
  const int col_base = gx * 256 + wn * 64 + m16;
#pragma unroll
  for (int mt = 0; mt < 8; ++mt) {
#pragma unroll
    for (int nt = 0; nt < 4; ++nt) {
      const int r0 = row_base + mt * 16;
      const int c  = col_base + nt * 16;
#pragma unroll
      for (int r = 0; r < 4; ++r)
        C[(size_t)(r0 + r) * OUT_DIM + c] = acc[mt][nt][r];
    }
  }
}

// ---------------------------------------------------------------------------
// TIER-2 (previous session's best, ws >= 88MB): on-the-fly A, 128^2 tile.
// ---------------------------------------------------------------------------
__global__ __launch_bounds__(256) void kan_prep(const float* __restrict__ x,
                                                const float* __restrict__ coef,
                                                const float* __restrict__ scale_base,
                                                const float* __restrict__ scale_sp,
                                                float* __restrict__ xT,
                                                u16* __restrict__ sil,
                                                u16* __restrict__ wt) {
  const int t = threadIdx.x;

  if (blockIdx.x < TR_BLOCKS) {
    __shared__ float tile[64][65];
    const int bi = blockIdx.x;
    const int n0 = (bi & 127) * 64;
    const int d0 = (bi >> 7) * 64;
    const int col = t & 63, rbase = t >> 6;
#pragma unroll
    for (int i = 0; i < 16; ++i) {
      const int r = rbase + i * 4;
      const float v = x[(size_t)(n0 + r) * IN_DIM + d0 + col];
      tile[r][col] = v;
      sil[(size_t)(n0 + r) * IN_DIM + d0 + col] =
          f2b(v * rcp_fast(1.0f + __expf(-v)));
    }
    __syncthreads();
#pragma unroll
    for (int i = 0; i < 16; ++i) {
      const int dd = rbase + i * 4;
      xT[(size_t)(d0 + dd) * NROWS + n0 + col] = tile[col][dd];
    }
  } else {
    __shared__ __align__(16) u16 tsp[WT_O][WT_D * 8 + 8];
    __shared__ __align__(16) u16 tsi[WT_O][WT_D + 8];
    const int bi = blockIdx.x - TR_BLOCKS;
    const int o0 = (bi % (OUT_DIM / WT_O)) * WT_O;
    const int d0 = (bi / (OUT_DIM / WT_O)) * WT_D;
    const int ol = t & (WT_O - 1), dl0 = t >> 4;
#pragma unroll
    for (int rep = 0; rep < WT_D / 16; ++rep) {
      const int dl = rep * 16 + dl0;
      const int d = d0 + dl, o = o0 + ol;
      const size_t doff = (size_t)d * OUT_DIM + o;
      const float ssp = scale_sp[doff];
      const float sbv = scale_base[doff];
      const float4* cp = (const float4*)(coef + doff * 8);
      float4 c0 = cp[0], c1 = cp[1];
      uint4 val;
      val.x = pkbf(c0.x * ssp, c0.y * ssp);
      val.y = pkbf(c0.z * ssp, c0.w * ssp);
      val.z = pkbf(c1.x * ssp, c1.y * ssp);
      val.w = pkbf(c1.z * ssp, c1.w * ssp);
      *(uint4*)&tsp[ol][dl * 8] = val;
      tsi[ol][dl] = f2b(sbv);
    }
    __syncthreads();
    for (int i = t; i < WT_O * 64; i += 256) {
      const int row = i >> 6, col = i & 63;
      *(uint4*)(wt + (size_t)(o0 + row) * KTOT + (size_t)(d0 + col) * 8) =
          *(const uint4*)&tsp[row][col * 8];
    }
    if (t < WT_O * 8) {
      const int row = t >> 3, col = t & 7;
      *(uint4*)(wt + (size_t)(o0 + row) * KTOT + KSPL + d0 + col * 8) =
          *(const uint4*)&tsi[row][col * 8];
    }
  }
}

__global__ __launch_bounds__(256) void kan_gemm(const float* __restrict__ xT,
                                                const u16* __restrict__ sil,
                                                const u16* __restrict__ Bt,
                                                float* __restrict__ C) {
  __shared__ __align__(16) u16 As[128 * 64];
  __shared__ __align__(16) u16 Bs[128 * 64];
  const int tid  = threadIdx.x;
  const int lane = tid & 63;
  const int w    = tid >> 6;
  const int wm   = w >> 1, wn = w & 1;
  const int q    = lane >> 4, m16 = lane & 15;
  const int gx = blockIdx.x, gy = blockIdx.y;

  f32x4 acc[4][4];
#pragma unroll
  for (int i = 0; i < 4; ++i)
#pragma unroll
    for (int j = 0; j < 4; ++j) acc[i][j] = (f32x4){0.f, 0.f, 0.f, 0.f};

  const int srow = lane >> 3;
  const int swzc = (lane & 7) ^ srow;
  const u16* gb0 = Bt + (size_t)(gx * 128) * KTOT + swzc * 8;
  const int r7 = m16 & 15 & 7;
  const int dgrp = tid >> 5;
  const int nh   = tid & 31;

  for (int kk = 0; kk < KTOT; kk += 64) {
#pragma unroll
    for (int i = 0; i < 4; ++i) {
      const int rg = w * 32 + i * 8;
      __builtin_amdgcn_global_load_lds((gptr_t)(gb0 + (size_t)(rg + srow) * KTOT + kk),
                                       (sptr_t)&Bs[rg * 64], 16, 0, 0);
    }
    if (kk < KSPL) {
      const int d = (kk >> 3) + dgrp;
      const float4 xv = *(const float4*)(xT + (size_t)d * NROWS + gy * 128 + nh * 4);
      const float xa[4] = {xv.x, xv.y, xv.z, xv.w};
#pragma unroll
      for (int r = 0; r < 4; ++r) {
        const int row = nh * 4 + r;
        const uint4 wv = basis_pack(xa[r]);
        *(uint4*)&As[row * 64 + ((dgrp ^ (row & 7)) * 8)] = wv;
      }
    } else {
      const int kb = kk - KSPL;
#pragma unroll
      for (int i = 0; i < 4; ++i) {
        const int rg = w * 32 + i * 8;
        __builtin_amdgcn_global_load_lds(
            (gptr_t)(sil + (size_t)(gy * 128 + rg + srow) * IN_DIM + kb + swzc * 8),
            (sptr_t)&As[rg * 64], 16, 0, 0);
      }
    }
    __syncthreads();
#pragma unroll
    for (int ks = 0; ks < 64; ks += 32) {
      const int pc = ((ks >> 3) + q) ^ r7;
      bf16x8 af[4], bf[4];
#pragma unroll
      for (int mt = 0; mt < 4; ++mt)
        af[mt] = *(const bf16x8*)&As[(wm * 64 + mt * 16 + m16) * 64 + pc * 8];
#pragma unroll
      for (int nt = 0; nt < 4; ++nt)
        bf[nt] = *(const bf16x8*)&Bs[(wn * 64 + nt * 16 + m16) * 64 + pc * 8];
#pragma unroll
      for (int mt = 0; mt < 4; ++mt)
#pragma unroll
        for (int nt = 0; nt < 4; ++nt)
          acc[mt][nt] = __builtin_amdgcn_mfma_f32_16x16x32_bf16(af[mt], bf[nt],
                                                                acc[mt][nt], 0, 0, 0);
    }
    __syncthreads();
  }

#pragma unroll
  for (int mt = 0; mt < 4; ++mt) {
    const int row0 = gy * 128 + wm * 64 + mt * 16 + q * 4;
#pragma unroll
    for (int nt = 0; nt < 4; ++nt) {
      const int col = gx * 128 + wn * 64 + nt * 16 + m16;
#pragma unroll
      for (int r = 0; r < 4; ++r)
        C[(size_t)(row0 + r) * OUT_DIM + col] = acc[mt][nt][r];
    }
  }
}

// ---------------------------------------------------------------------------
// Fallback (workspace too small): fused direct fp32 computation.
// ---------------------------------------------------------------------------
__global__ __launch_bounds__(256) void kan_fallback(const float* __restrict__ x,
                                                    const float* __restrict__ grid,
                                                    const float* __restrict__ coef,
                                                    const float* __restrict__ scale_base,
                                                    const float* __restrict__ scale_sp,
                                                    float* __restrict__ out) {
  __shared__ float bs[IN_DIM * 9];  // 36 KB
  const int n = blockIdx.x;
  const int t = threadIdx.x;
#pragma unroll
  for (int dd = 0; dd < IN_DIM / 256; ++dd) {
    const int d = t + dd * 256;
    const float xv = x[(size_t)n * IN_DIM + d];
    float tt = (xv + 1.0f) * 2.5f;
    float jf = floorf(tt);
    jf = fminf(fmaxf(jf, 0.0f), 4.0f);
    const float u = tt - jf;
    const int j = (int)jf;
    const float um = 1.0f - u;
    const float u2 = u * u, u3 = u2 * u;
    float* r = &bs[d * 9];
#pragma unroll
    for (int g = 0; g < NB; ++g) r[g] = 0.0f;
    r[j]     = um * um * um * (1.0f / 6.0f);
    r[j + 1] = (3.0f * u3 - 6.0f * u2 + 4.0f) * (1.0f / 6.0f);
    r[j + 2] = (-3.0f * u3 + 3.0f * u2 + 3.0f * u + 1.0f) * (1.0f / 6.0f);
    r[j + 3] = u3 * (1.0f / 6.0f);
    r[8]     = xv * rcp_fast(1.0f + __expf(-xv));
  }
  __syncthreads();
  const int o = blockIdx.y * 256 + t;
  float acc = 0.0f;
  for (int d = 0; d < IN_DIM; ++d) {
    const size_t doff = (size_t)d * OUT_DIM + o;
    const float4* cp = (const float4*)(coef + doff * 8);
    float4 c0 = cp[0], c1 = cp[1];
    const float* b = &bs[d * 9];
    float s = b[0] * c0.x + b[1] * c0.y + b[2] * c0.z + b[3] * c0.w +
              b[4] * c1.x + b[5] * c1.y + b[6] * c1.z + b[7] * c1.w;
    acc += s * scale_sp[doff] + b[8] * scale_base[doff];
  }
  out[(size_t)n * OUT_DIM + o] = acc;
}

extern "C" void kernel_launch(void* const* d_in, const int* in_sizes, int n_in,
                              void* d_out, int out_size, void* d_ws, size_t ws_size,
                              hipStream_t stream) {
  const float* x  = (const float*)d_in[0];  // (4,2048,1024)
  const float* gr = (const float*)d_in[1];  // (1024,12)  (uniform; unused in fast path)
  const float* cf = (const float*)d_in[2];  // (1024,2048,8)
  const float* sb = (const float*)d_in[3];  // (1024,2048)
  const float* sp = (const float*)d_in[4];  // (1024,2048)
  float* out = (float*)d_out;               // (4,2048,2048)

  const size_t act_bytes = (size_t)NROWS * KTOT * sizeof(u16);    // 151 MB
  const size_t wt_bytes  = (size_t)OUT_DIM * KTOT * sizeof(u16);  // 37.7 MB
  const size_t need1 = act_bytes + wt_bytes;                      // ~189 MB

  const size_t xT_bytes  = (size_t)IN_DIM * NROWS * sizeof(float);  // 33.5 MB
  const size_t sil_bytes = (size_t)NROWS * IN_DIM * sizeof(u16);    // 16.8 MB
  const size_t need2 = xT_bytes + sil_bytes + wt_bytes;             // ~88 MB

  if (ws_size >= need1) {
    u16* act = (u16*)d_ws;
    u16* wt  = (u16*)((char*)d_ws + act_bytes);
    kan_prep2<<<dim3(ACT_BLOCKS + WT_BLOCKS), dim3(256), 0, stream>>>(
        x, cf, sb, sp, act, wt);
    kan_gemm2<<<dim3(256), dim3(512), 0, stream>>>(act, wt, out);
  } else if (ws_size >= need2) {
    float* xT = (float*)d_ws;
    u16* sil  = (u16*)((char*)d_ws + xT_bytes);
    u16* wt   = (u16*)((char*)d_ws + xT_bytes + sil_bytes);
    kan_prep<<<dim3(TR_BLOCKS + WT_BLOCKS), dim3(256), 0, stream>>>(
        x, cf, sb, sp, xT, sil, wt);
    kan_gemm<<<dim3(OUT_DIM / 128, NROWS / 128), dim3(256), 0, stream>>>(
        xT, sil, wt, out);
  } else {
    kan_fallback<<<dim3(NROWS, OUT_DIM / 256), dim3(256), 0, stream>>>(x, gr, cf, sb, sp, out);
  }
}